// Round 12
// baseline (345.548 us; speedup 1.0000x reference)
//
#include <hip/hip_runtime.h>

// EquivariantLinear: out[pos, c, m] = pw * sum_k x[pos, k, m] * W_{l(m)}[k, c]
// pos = 32768, C_IN = C_OUT = 256, FEAT = 9 (irreps 1,3,5), pw = 1/16.
// R14: PRODUCER-CONSUMER WAVE SPECIALIZATION (first true phase-overlap).
//  - 256 blocks x 512 thr (8 waves), 1 block/CU, NT=8 tiles of POSB=16.
//    LDS = 2 x 76032 B double buffer (152 KB).
//  - Waves 0-3 = producers: stage tile t+1 (36-B-unit loads, cvt_pk, b16
//    ds_write) into buf[(t+1)&1] while waves 4-7 = consumers compute tile t
//    from buf[t&1]. Wave->SIMD round-robin puts 1 producer + 1 consumer per
//    SIMD (the m114-verified MFMA/VALU co-issue pairing).
//  - Consumers: 64 channels each (acc = 144 regs, producers hold none ->
//    register wall sidestepped). Output via R5 register-direct nt stores
//    (36 B/lane per (pos,c); proven neutral) -> no stgw LDS, no aliasing.
//  - ONE raw barrier per tile (s_barrier + lgkmcnt(0)); vmcnt NEVER drained
//    in-loop: nt stores fire-and-forget, producer load waits are
//    compiler-counted on register use.

typedef float f32x4 __attribute__((ext_vector_type(4)));
typedef float f32x4u __attribute__((ext_vector_type(4), aligned(4)));
typedef short s16x8 __attribute__((ext_vector_type(8)));

#define POSB 16                       // positions per tile
#define XS_KS 264                     // padded k-stride (elems)
#define XS_MS (POSB * XS_KS)          // 4224 elems per m-plane
#define BUF_BYTES (9 * XS_MS * 2)     // 76032 B per buffer
#define SMEM_BYTES (2 * BUF_BYTES)    // 152064 B -> 1 block/CU
#define NT 8                          // tiles per block; 256 x 8 = 2048 tiles
#define TILE_FLOATS (POSB * 2304)     // 36864

__device__ __forceinline__ unsigned short f2bf(float f) {
  unsigned u = __float_as_uint(f);
  return (unsigned short)((u + 0x7FFFu + ((u >> 16) & 1u)) >> 16);
}

__device__ __forceinline__ unsigned cvt_pk_bf16(float lo, float hi) {
  unsigned r;
  asm("v_cvt_pk_bf16_f32 %0, %1, %2" : "=v"(r) : "v"(lo), "v"(hi));
  return r;
}

// raw barrier: LDS ordering only, no vmcnt drain (stores stay in flight)
__device__ __forceinline__ void bar_nodrain() {
  asm volatile("s_waitcnt lgkmcnt(0)\n\ts_barrier" ::: "memory");
}

// ---- prep: W^T bf16 image in ws: wt[irr][c][k] = pw * w_irr[k][c] ----
__global__ void prep_w(const float* __restrict__ w0, const float* __restrict__ w1,
                       const float* __restrict__ w2, unsigned short* __restrict__ wt) {
  const int b = blockIdx.x;
  const int irr = b / 16;
  const int tile = b % 16;
  const int k0 = (tile >> 2) << 6;
  const int c0 = (tile & 3) << 6;
  const float* w = (irr == 0) ? w0 : ((irr == 1) ? w1 : w2);
  __shared__ float lt[64 * 65];
  const int t = threadIdx.x;
#pragma unroll
  for (int i = 0; i < 16; ++i) {
    int e = t + (i << 8);
    int kk = e >> 6, cc = e & 63;
    lt[cc * 65 + kk] = w[(k0 + kk) * 256 + (c0 + cc)];
  }
  __syncthreads();
#pragma unroll
  for (int i = 0; i < 16; ++i) {
    int e = t + (i << 8);
    int cc = e >> 6, kk = e & 63;
    wt[irr * 65536 + (c0 + cc) * 256 + (k0 + kk)] = f2bf(lt[cc * 65 + kk] * 0.0625f);
  }
}

// producer: stage 8 (pos,k) 36-B units; lane tp in [0,256), pos = i0+i, k = tp
__device__ __forceinline__ void stage_chunk(const float* __restrict__ xb,
                                            unsigned short* __restrict__ xs,
                                            int tp, int i0) {
  f32x4u va[8], vb[8];
  float vc[8];
#pragma unroll
  for (int i = 0; i < 8; ++i) {
    const float* s = xb + (((i0 + i) << 8) + tp) * 9;
    va[i] = *reinterpret_cast<const f32x4u*>(s);
    vb[i] = *reinterpret_cast<const f32x4u*>(s + 4);
    vc[i] = s[8];
  }
#pragma unroll
  for (int i = 0; i < 8; ++i) {
    unsigned short* base = xs + (i0 + i) * XS_KS + tp;
    unsigned p01 = cvt_pk_bf16(va[i][0], va[i][1]);
    unsigned p23 = cvt_pk_bf16(va[i][2], va[i][3]);
    unsigned p45 = cvt_pk_bf16(vb[i][0], vb[i][1]);
    unsigned p67 = cvt_pk_bf16(vb[i][2], vb[i][3]);
    base[0 * XS_MS] = (unsigned short)p01;
    base[1 * XS_MS] = (unsigned short)(p01 >> 16);
    base[2 * XS_MS] = (unsigned short)p23;
    base[3 * XS_MS] = (unsigned short)(p23 >> 16);
    base[4 * XS_MS] = (unsigned short)p45;
    base[5 * XS_MS] = (unsigned short)(p45 >> 16);
    base[6 * XS_MS] = (unsigned short)p67;
    base[7 * XS_MS] = (unsigned short)(p67 >> 16);
    base[8 * XS_MS] = f2bf(vc[i]);
  }
}

// ---- main: 256 blocks x 512 threads, 1 block/CU, NT=8 tiles ----
__global__ __launch_bounds__(512, 2) void eqlin_main(
    const float* __restrict__ x, const unsigned short* __restrict__ wt,
    float* __restrict__ out) {
  extern __shared__ char smem[];

  const int t = threadIdx.x;
  const long long blk = blockIdx.x;
  const float* xbase = x + blk * ((long long)NT * TILE_FLOATS);
  const int w = t >> 6;

  if (w < 4) {
    // ================= PRODUCER (waves 0-3, 256 lanes) =================
    const int tp = t;  // 0..255
    unsigned short* buf0 = reinterpret_cast<unsigned short*>(smem);
    stage_chunk(xbase, buf0, tp, 0);
    stage_chunk(xbase, buf0, tp, 8);
    bar_nodrain();
#pragma unroll 1
    for (int it = 0; it < NT; ++it) {
      if (it + 1 < NT) {
        const float* xb = xbase + (long long)(it + 1) * TILE_FLOATS;
        unsigned short* bn =
            reinterpret_cast<unsigned short*>(smem + ((it + 1) & 1) * BUF_BYTES);
        stage_chunk(xb, bn, tp, 0);
        stage_chunk(xb, bn, tp, 8);
      }
      bar_nodrain();
    }
  } else {
    // ================= CONSUMER (waves 4-7, 64 ch each) =================
    const int wv = w - 4;
    const int l = t & 63;
    const int cr = l & 15;          // A row sel / B col (c in 16-wide group)
    const int g = l >> 4;           // 0..3
    const int kg = g << 3;          // k-chunk base 0/8/16/24
    const int c0 = wv << 6;         // 64 channels per consumer wave
    const unsigned short* wtB = wt + (c0 + cr) * 256 + kg;

    bar_nodrain();  // matches producer prologue barrier
#pragma unroll 1
    for (int it = 0; it < NT; ++it) {
      const unsigned short* xsb =
          reinterpret_cast<const unsigned short*>(smem + (it & 1) * BUF_BYTES);
      const unsigned short* xsA = xsb + cr * XS_KS + kg;

      f32x4 accA[4][4];  // [m][ct], m = 0..3
#pragma unroll
      for (int m = 0; m < 4; ++m)
#pragma unroll
        for (int ct = 0; ct < 4; ++ct) accA[m][ct] = (f32x4){0.f, 0.f, 0.f, 0.f};

      // pass 1: m 0..3 (irr0 for m0, irr1 for m1..3)
#pragma unroll 2
      for (int ks = 0; ks < 8; ++ks) {
        const int kk = ks << 5;
        s16x8 a0 = *reinterpret_cast<const s16x8*>(xsA + kk);
        s16x8 a1 = *reinterpret_cast<const s16x8*>(xsA + 1 * XS_MS + kk);
        s16x8 a2 = *reinterpret_cast<const s16x8*>(xsA + 2 * XS_MS + kk);
        s16x8 a3 = *reinterpret_cast<const s16x8*>(xsA + 3 * XS_MS + kk);
#pragma unroll
        for (int ct = 0; ct < 4; ++ct) {
          const unsigned short* wc = wtB + ct * 4096 + kk;
          s16x8 b0 = *reinterpret_cast<const s16x8*>(wc);            // irr0
          s16x8 b1 = *reinterpret_cast<const s16x8*>(wc + 65536);    // irr1
          accA[0][ct] = __builtin_amdgcn_mfma_f32_16x16x32_bf16(a0, b0, accA[0][ct], 0, 0, 0);
          accA[1][ct] = __builtin_amdgcn_mfma_f32_16x16x32_bf16(a1, b1, accA[1][ct], 0, 0, 0);
          accA[2][ct] = __builtin_amdgcn_mfma_f32_16x16x32_bf16(a2, b1, accA[2][ct], 0, 0, 0);
          accA[3][ct] = __builtin_amdgcn_mfma_f32_16x16x32_bf16(a3, b1, accA[3][ct], 0, 0, 0);
        }
      }

      f32x4 accB[5][4];  // [m-4][ct], m = 4..8 (irr2)
#pragma unroll
      for (int m = 0; m < 5; ++m)
#pragma unroll
        for (int ct = 0; ct < 4; ++ct) accB[m][ct] = (f32x4){0.f, 0.f, 0.f, 0.f};

      // pass 2: m 4..8
#pragma unroll 2
      for (int ks = 0; ks < 8; ++ks) {
        const int kk = ks << 5;
        s16x8 a4 = *reinterpret_cast<const s16x8*>(xsA + 4 * XS_MS + kk);
        s16x8 a5 = *reinterpret_cast<const s16x8*>(xsA + 5 * XS_MS + kk);
        s16x8 a6 = *reinterpret_cast<const s16x8*>(xsA + 6 * XS_MS + kk);
        s16x8 a7 = *reinterpret_cast<const s16x8*>(xsA + 7 * XS_MS + kk);
        s16x8 a8 = *reinterpret_cast<const s16x8*>(xsA + 8 * XS_MS + kk);
#pragma unroll
        for (int ct = 0; ct < 4; ++ct) {
          const unsigned short* wc = wtB + ct * 4096 + kk;
          s16x8 b2 = *reinterpret_cast<const s16x8*>(wc + 131072);   // irr2
          accB[0][ct] = __builtin_amdgcn_mfma_f32_16x16x32_bf16(a4, b2, accB[0][ct], 0, 0, 0);
          accB[1][ct] = __builtin_amdgcn_mfma_f32_16x16x32_bf16(a5, b2, accB[1][ct], 0, 0, 0);
          accB[2][ct] = __builtin_amdgcn_mfma_f32_16x16x32_bf16(a6, b2, accB[2][ct], 0, 0, 0);
          accB[3][ct] = __builtin_amdgcn_mfma_f32_16x16x32_bf16(a7, b2, accB[3][ct], 0, 0, 0);
          accB[4][ct] = __builtin_amdgcn_mfma_f32_16x16x32_bf16(a8, b2, accB[4][ct], 0, 0, 0);
        }
      }

      // ---- register-direct nt stores: lane (g,cr) owns (pos=4g+j, c),
      //      all 9 m contiguous (36 B = dwordx4 + dwordx4 + dword) ----
      const long long obase = (long long)(blk * NT + it) * TILE_FLOATS;
#pragma unroll
      for (int ct = 0; ct < 4; ++ct) {
        const int c = c0 + (ct << 4) + cr;
#pragma unroll
        for (int j = 0; j < 4; ++j) {
          float* o = out + obase + (((g << 2) + j) * 256 + c) * 9;
          f32x4u v0 = {accA[0][ct][j], accA[1][ct][j], accA[2][ct][j], accA[3][ct][j]};
          f32x4u v1 = {accB[0][ct][j], accB[1][ct][j], accB[2][ct][j], accB[3][ct][j]};
          __builtin_nontemporal_store(v0, reinterpret_cast<f32x4u*>(o));
          __builtin_nontemporal_store(v1, reinterpret_cast<f32x4u*>(o + 4));
          __builtin_nontemporal_store(accB[4][ct][j], o + 8);
        }
      }
      bar_nodrain();  // buf[it&1] consumed; producers' buf[(it+1)&1] complete
    }
  }
}

extern "C" void kernel_launch(void* const* d_in, const int* in_sizes, int n_in,
                              void* d_out, int out_size, void* d_ws, size_t ws_size,
                              hipStream_t stream) {
  const float* x = (const float*)d_in[0];
  const float* w0 = (const float*)d_in[1];
  const float* w1 = (const float*)d_in[2];
  const float* w2 = (const float*)d_in[3];
  unsigned short* wt = (unsigned short*)d_ws;  // 3*256*256 bf16 = 384 KB
  float* out = (float*)d_out;

  prep_w<<<48, 256, 0, stream>>>(w0, w1, w2, wt);

  (void)hipFuncSetAttribute(reinterpret_cast<const void*>(eqlin_main),
                            hipFuncAttributeMaxDynamicSharedMemorySize, SMEM_BYTES);
  eqlin_main<<<256, 512, SMEM_BYTES, stream>>>(x, wt, out);
}

// Round 13
// 162.850 us; speedup vs baseline: 2.1219x; 2.1219x over previous
//
#include <hip/hip_runtime.h>

// EquivariantLinear: out[pos, c, m] = pw * sum_k x[pos, k, m] * W_{l(m)}[k, c]
// pos = 32768, C_IN = C_OUT = 256, FEAT = 9 (irreps 1,3,5), pw = 1/16.
// R15 = R8 restored verbatim (session champion, 162.7 us wall).
// Structure: 2048 blocks x 512 thr, POSB=16, 76KB LDS, 2 blocks/CU.
//  - stage: 36-B-unit coalesced loads (8/thread), cvt_pk_bf16 converts,
//    conflict-free b16 LDS scatter to [m][pos][k] image.
//  - compute: two-pass 16x16x32 bf16 MFMA (m0-3 then m4-8), 32 ch/wave.
//  - out: per-wave LDS re-stage -> coalesced float4 NON-TEMPORAL stores
//    (out is write-once; nt keeps it from thrashing L2/L3 against x reads
//    -> +10%, the largest single win of the session).
// 14-round ledger: all overlap/occupancy levers die on store-drain /
// 128-reg-16-wave wall / 1-block-CU serialization; only contention
// reducers (nt stores, coalescing) won. This is the empirical floor of
// this formulation (~50% HBM duty; memory floor ~96 us unreachable here).

typedef float f32x4 __attribute__((ext_vector_type(4)));
typedef float f32x4u __attribute__((ext_vector_type(4), aligned(4)));
typedef short s16x8 __attribute__((ext_vector_type(8)));

#define POSB 16                      // positions per block
#define XS_KS 264                    // padded k-stride (elems)
#define XS_MS (POSB * XS_KS)         // 4224 elems per m-plane
#define SMEM_BYTES (9 * XS_MS * 2)   // 76032 B
#define STG_ROW 148                  // out-stage row stride (floats); row=144 used
// per-wave out-stage: 16*148*4 = 9472 B; 8 waves = 75776 <= 76032 (aliases xs)

__device__ __forceinline__ unsigned short f2bf(float f) {
  unsigned u = __float_as_uint(f);
  return (unsigned short)((u + 0x7FFFu + ((u >> 16) & 1u)) >> 16);
}

__device__ __forceinline__ unsigned cvt_pk_bf16(float lo, float hi) {
  unsigned r;
  asm("v_cvt_pk_bf16_f32 %0, %1, %2" : "=v"(r) : "v"(lo), "v"(hi));
  return r;
}

// ---- prep: W^T bf16 image in ws: wt[irr][c][k] = pw * w_irr[k][c] ----
__global__ void prep_w(const float* __restrict__ w0, const float* __restrict__ w1,
                       const float* __restrict__ w2, unsigned short* __restrict__ wt) {
  const int b = blockIdx.x;
  const int irr = b / 16;
  const int tile = b % 16;
  const int k0 = (tile >> 2) << 6;
  const int c0 = (tile & 3) << 6;
  const float* w = (irr == 0) ? w0 : ((irr == 1) ? w1 : w2);
  __shared__ float lt[64 * 65];
  const int t = threadIdx.x;
#pragma unroll
  for (int i = 0; i < 16; ++i) {
    int e = t + (i << 8);
    int kk = e >> 6, cc = e & 63;
    lt[cc * 65 + kk] = w[(k0 + kk) * 256 + (c0 + cc)];
  }
  __syncthreads();
#pragma unroll
  for (int i = 0; i < 16; ++i) {
    int e = t + (i << 8);
    int cc = e >> 6, kk = e & 63;
    wt[irr * 65536 + (c0 + cc) * 256 + (k0 + kk)] = f2bf(lt[cc * 65 + kk] * 0.0625f);
  }
}

// ---- main: 2048 blocks x 512 threads (8 waves), 2 blocks/CU ----
__global__ __launch_bounds__(512, 4) void eqlin_main(
    const float* __restrict__ x, const unsigned short* __restrict__ wt,
    float* __restrict__ out) {
  extern __shared__ char smem[];
  unsigned short* xs = reinterpret_cast<unsigned short*>(smem);  // [9][16][264] bf16

  const int t = threadIdx.x;
  const long long blk = blockIdx.x;
  const float* xb = x + blk * (POSB * 2304);

  // ---- stage x -> LDS bf16 [m][pos][k]: 4096 36-B units, 8 per thread ----
  {
    f32x4u va[8], vb[8];
    float vc[8];
#pragma unroll
    for (int i = 0; i < 8; ++i) {
      const float* s = xb + (t + (i << 9)) * 9;
      va[i] = *reinterpret_cast<const f32x4u*>(s);
      vb[i] = *reinterpret_cast<const f32x4u*>(s + 4);
      vc[i] = s[8];
    }
#pragma unroll
    for (int i = 0; i < 8; ++i) {
      const int u = t + (i << 9);
      const int pos = u >> 8;        // 0..15
      const int k = u & 255;
      unsigned short* base = xs + pos * XS_KS + k;
      unsigned p01 = cvt_pk_bf16(va[i][0], va[i][1]);
      unsigned p23 = cvt_pk_bf16(va[i][2], va[i][3]);
      unsigned p45 = cvt_pk_bf16(vb[i][0], vb[i][1]);
      unsigned p67 = cvt_pk_bf16(vb[i][2], vb[i][3]);
      base[0 * XS_MS] = (unsigned short)p01;
      base[1 * XS_MS] = (unsigned short)(p01 >> 16);
      base[2 * XS_MS] = (unsigned short)p23;
      base[3 * XS_MS] = (unsigned short)(p23 >> 16);
      base[4 * XS_MS] = (unsigned short)p45;
      base[5 * XS_MS] = (unsigned short)(p45 >> 16);
      base[6 * XS_MS] = (unsigned short)p67;
      base[7 * XS_MS] = (unsigned short)(p67 >> 16);
      base[8 * XS_MS] = f2bf(vc[i]);
    }
  }
  __syncthreads();

  const int w = t >> 6;
  const int l = t & 63;
  const int cr = l & 15;          // A row (=pos) / B col (=c in tile)
  const int kg = (l >> 4) << 3;   // k-chunk base 0/8/16/24
  const int c0 = w << 5;          // 32 channels per wave

  const unsigned short* xsA = xs + cr * XS_KS + kg;
  const unsigned short* wtB = wt + (c0 + cr) * 256 + kg;

  f32x4 accA[4][2];  // m = 0..3
#pragma unroll
  for (int m = 0; m < 4; ++m)
#pragma unroll
    for (int ct = 0; ct < 2; ++ct) accA[m][ct] = (f32x4){0.f, 0.f, 0.f, 0.f};

  // pass 1: m 0..3 (irr0 for m0, irr1 for m1..3)
#pragma unroll 2
  for (int ks = 0; ks < 8; ++ks) {
    const int kk = ks << 5;
    s16x8 b00 = *reinterpret_cast<const s16x8*>(wtB + kk);
    s16x8 b01 = *reinterpret_cast<const s16x8*>(wtB + 4096 + kk);
    s16x8 b10 = *reinterpret_cast<const s16x8*>(wtB + 65536 + kk);
    s16x8 b11 = *reinterpret_cast<const s16x8*>(wtB + 65536 + 4096 + kk);
    {
      s16x8 a = *reinterpret_cast<const s16x8*>(xsA + kk);
      accA[0][0] = __builtin_amdgcn_mfma_f32_16x16x32_bf16(a, b00, accA[0][0], 0, 0, 0);
      accA[0][1] = __builtin_amdgcn_mfma_f32_16x16x32_bf16(a, b01, accA[0][1], 0, 0, 0);
    }
#pragma unroll
    for (int m = 1; m < 4; ++m) {
      s16x8 a = *reinterpret_cast<const s16x8*>(xsA + m * XS_MS + kk);
      accA[m][0] = __builtin_amdgcn_mfma_f32_16x16x32_bf16(a, b10, accA[m][0], 0, 0, 0);
      accA[m][1] = __builtin_amdgcn_mfma_f32_16x16x32_bf16(a, b11, accA[m][1], 0, 0, 0);
    }
  }

  f32x4 accB[5][2];  // m = 4..8 (irr2)
#pragma unroll
  for (int m = 0; m < 5; ++m)
#pragma unroll
    for (int ct = 0; ct < 2; ++ct) accB[m][ct] = (f32x4){0.f, 0.f, 0.f, 0.f};

  // pass 2: m 4..8
#pragma unroll 2
  for (int ks = 0; ks < 8; ++ks) {
    const int kk = ks << 5;
    s16x8 b20 = *reinterpret_cast<const s16x8*>(wtB + 2 * 65536 + kk);
    s16x8 b21 = *reinterpret_cast<const s16x8*>(wtB + 2 * 65536 + 4096 + kk);
#pragma unroll
    for (int m = 0; m < 5; ++m) {
      s16x8 a = *reinterpret_cast<const s16x8*>(xsA + (m + 4) * XS_MS + kk);
      accB[m][0] = __builtin_amdgcn_mfma_f32_16x16x32_bf16(a, b20, accB[m][0], 0, 0, 0);
      accB[m][1] = __builtin_amdgcn_mfma_f32_16x16x32_bf16(a, b21, accB[m][1], 0, 0, 0);
    }
  }
  __syncthreads();  // xs fully consumed by ALL waves; stage may alias it

  // ---- per-wave out-stage (9472 B slice of smem), wave-internal sync only ----
  float* stgw = reinterpret_cast<float*>(smem) + w * (POSB * STG_ROW);
  const int posb = (l >> 4) << 2;
  f32x4* o4 = reinterpret_cast<f32x4*>(out) + blk * 9216 + w * 72;

#pragma unroll
  for (int ct = 0; ct < 2; ++ct) {
    // scatter acc -> stgw[pos][cr*9 + m]  (fp32, ~2-way banks: free)
#pragma unroll
    for (int m = 0; m < 9; ++m) {
#pragma unroll
      for (int j = 0; j < 4; ++j) {
        float v = (m < 4) ? accA[m][ct][j] : accB[m - 4][ct][j];
        stgw[(posb + j) * STG_ROW + cr * 9 + m] = v;
      }
    }
    asm volatile("s_waitcnt lgkmcnt(0)" ::: "memory");
    // coalesced float4 NON-TEMPORAL store of this wave's 16c x 9m slice
#pragma unroll
    for (int q = 0; q < 9; ++q) {
      const int e = l + (q << 6);                 // 0..575 float4s
      const int pos = (int)((unsigned)e / 36u);
      const int rem = e - pos * 36;
      f32x4 v = *reinterpret_cast<const f32x4*>(stgw + pos * STG_ROW + (rem << 2));
      __builtin_nontemporal_store(v, &o4[pos * 576 + ct * 36 + rem]);
    }
    asm volatile("s_waitcnt lgkmcnt(0)" ::: "memory");  // drain reads before next ct writes
  }
}

extern "C" void kernel_launch(void* const* d_in, const int* in_sizes, int n_in,
                              void* d_out, int out_size, void* d_ws, size_t ws_size,
                              hipStream_t stream) {
  const float* x = (const float*)d_in[0];
  const float* w0 = (const float*)d_in[1];
  const float* w1 = (const float*)d_in[2];
  const float* w2 = (const float*)d_in[3];
  unsigned short* wt = (unsigned short*)d_ws;  // 3*256*256 bf16 = 384 KB
  float* out = (float*)d_out;

  prep_w<<<48, 256, 0, stream>>>(w0, w1, w2, wt);

  (void)hipFuncSetAttribute(reinterpret_cast<const void*>(eqlin_main),
                            hipFuncAttributeMaxDynamicSharedMemorySize, SMEM_BYTES);
  eqlin_main<<<2048, 512, SMEM_BYTES, stream>>>(x, wt, out);
}